// Round 1
// baseline (224.164 us; speedup 1.0000x reference)
//
#include <hip/hip_runtime.h>
#include <stdint.h>

#define Mdim 4096
#define Kdim 4096
#define Ndim 4096

typedef __attribute__((ext_vector_type(8))) short bf16x8;   // 8 bf16 = 4 VGPRs (MFMA A/B frag)
typedef __attribute__((ext_vector_type(4))) float f32x4;    // MFMA C/D frag

// f32 -> bf16 round-to-nearest-even
static __device__ __forceinline__ unsigned short f2bf_rne(float f) {
    union { float f; unsigned u; } v; v.f = f;
    unsigned u = v.u;
    u += 0x7FFFu + ((u >> 16) & 1u);
    return (unsigned short)(u >> 16);
}

// async global->LDS, 16B per lane. LDS dest = wave-uniform base + lane*16 (linear!).
static __device__ __forceinline__ void gload_lds16(const unsigned short* g, unsigned short* l) {
    __builtin_amdgcn_global_load_lds(
        (const __attribute__((address_space(1))) unsigned int*)g,
        (__attribute__((address_space(3))) unsigned int*)l,
        16, 0, 0);
}

// ---------------------------------------------------------------------------
// Conversion kernels: f32 -> bf16 (A linear, B transposed so GEMM sees B^T)
// ---------------------------------------------------------------------------
__global__ void conv_a(const float* __restrict__ a, unsigned short* __restrict__ out) {
    size_t idx = (size_t)blockIdx.x * blockDim.x + threadIdx.x;  // one float4 per thread
    float4 v = ((const float4*)a)[idx];
    ushort4 o;
    o.x = f2bf_rne(v.x); o.y = f2bf_rne(v.y); o.z = f2bf_rne(v.z); o.w = f2bf_rne(v.w);
    ((ushort4*)out)[idx] = o;
}

// y is K x N row-major; emit B^T = N x K row-major bf16 (64x64 tiles via LDS, +1 pad)
__global__ void conv_bt(const float* __restrict__ b, unsigned short* __restrict__ bt) {
    __shared__ float tile[64][65];
    const int tn = blockIdx.x;  // n-tile
    const int tk = blockIdx.y;  // k-tile
    for (int i = threadIdx.x; i < 64 * 64; i += 256) {
        int r = i >> 6, c = i & 63;  // r = k row, c = n col (coalesced read)
        tile[r][c] = b[(size_t)(tk * 64 + r) * Ndim + tn * 64 + c];
    }
    __syncthreads();
    for (int i = threadIdx.x; i < 64 * 64; i += 256) {
        int n = i >> 6, k = i & 63;  // bank = (k + n) % 32 -> conflict-free
        bt[(size_t)(tn * 64 + n) * Kdim + tk * 64 + k] = f2bf_rne(tile[k][n]);
    }
}

// ---------------------------------------------------------------------------
// bf16 GEMM, C = A * B with B given as B^T (N x K). m97 structure:
// 128x128 tile, BK=32, 4 waves (2x2), each wave 64x64 = 4x4 16x16 frags,
// global_load_lds width 16, 2 barriers per K-step.
// ---------------------------------------------------------------------------
__global__ __launch_bounds__(256) void gemm_bt(const unsigned short* __restrict__ A,
                                               const unsigned short* __restrict__ Bt,
                                               float* __restrict__ C) {
    __shared__ unsigned short lA[128 * 32];  // 8 KiB, row-major [128][32]
    __shared__ unsigned short lB[128 * 32];  // 8 KiB, row-major [128][32] (rows = n)

    const int tid  = threadIdx.x;
    const int lane = tid & 63;
    const int wid  = tid >> 6;        // 0..3
    const int wr   = wid >> 1;        // wave row (0..1)
    const int wc   = wid & 1;         // wave col (0..1)
    const int bm   = blockIdx.y;
    const int bn   = blockIdx.x;

    // staging: each wave issues 2 A-loads + 2 B-loads per K-step (16 rows each)
    // lane l covers row base+(l>>2), byte chunk (l&3)*16  => LDS linear base + l*16
    const int ra0 = (wid * 2 + 0) * 16 + (lane >> 2);
    const int ra1 = (wid * 2 + 1) * 16 + (lane >> 2);
    const int cch = (lane & 3) * 8;  // element offset of this lane's 16B chunk

    const unsigned short* gA0 = A  + ((size_t)(bm * 128 + ra0) << 12) + cch;
    const unsigned short* gA1 = A  + ((size_t)(bm * 128 + ra1) << 12) + cch;
    const unsigned short* gB0 = Bt + ((size_t)(bn * 128 + ra0) << 12) + cch;
    const unsigned short* gB1 = Bt + ((size_t)(bn * 128 + ra1) << 12) + cch;

    unsigned short* lA0 = lA + (wid * 2 + 0) * 512;  // 512 elems = 1024 B per wave-instr
    unsigned short* lA1 = lA + (wid * 2 + 1) * 512;
    unsigned short* lB0 = lB + (wid * 2 + 0) * 512;
    unsigned short* lB1 = lB + (wid * 2 + 1) * 512;

    f32x4 acc[4][4] = {};

    const int fr   = lane & 15;          // fragment row/col within 16
    const int koff = (lane >> 4) * 8;    // k-chunk per lane

    for (int k0 = 0; k0 < Kdim; k0 += 32) {
        gload_lds16(gA0 + k0, lA0);
        gload_lds16(gA1 + k0, lA1);
        gload_lds16(gB0 + k0, lB0);
        gload_lds16(gB1 + k0, lB1);
        __syncthreads();   // compiler emits vmcnt(0) drain before s_barrier

        bf16x8 af[4], bfr[4];
#pragma unroll
        for (int m = 0; m < 4; ++m)
            af[m] = *(const bf16x8*)&lA[(wr * 64 + m * 16 + fr) * 32 + koff];
#pragma unroll
        for (int n = 0; n < 4; ++n)
            bfr[n] = *(const bf16x8*)&lB[(wc * 64 + n * 16 + fr) * 32 + koff];

#pragma unroll
        for (int m = 0; m < 4; ++m)
#pragma unroll
            for (int n = 0; n < 4; ++n)
                acc[m][n] = __builtin_amdgcn_mfma_f32_16x16x32_bf16(af[m], bfr[n], acc[m][n], 0, 0, 0);

        __syncthreads();
    }

    // epilogue: C/D layout col = lane&15, row = (lane>>4)*4 + reg
    const int crow0 = bm * 128 + wr * 64 + (lane >> 4) * 4;
    const int ccol0 = bn * 128 + wc * 64 + (lane & 15);
#pragma unroll
    for (int m = 0; m < 4; ++m)
#pragma unroll
        for (int n = 0; n < 4; ++n) {
            int row = crow0 + m * 16;
            int col = ccol0 + n * 16;
#pragma unroll
            for (int r = 0; r < 4; ++r)
                C[(size_t)(row + r) * Ndim + col] = acc[m][n][r];
        }
}

// ---------------------------------------------------------------------------
// Fallback (only if workspace is too small for bf16 copies): plain f32 tiles
// ---------------------------------------------------------------------------
__global__ void gemm_f32_naive(const float* __restrict__ A, const float* __restrict__ B,
                               float* __restrict__ C) {
    __shared__ float As[32][33], Bs[32][33];
    const int tx = threadIdx.x & 31, ty = threadIdx.x >> 5;  // 32 x 8
    const int row0 = blockIdx.y * 32, col0 = blockIdx.x * 32;
    float acc[4] = {0.f, 0.f, 0.f, 0.f};
    for (int k0 = 0; k0 < Kdim; k0 += 32) {
        for (int i = threadIdx.x; i < 32 * 32; i += 256) {
            int r = i >> 5, c = i & 31;
            As[r][c] = A[(size_t)(row0 + r) * Kdim + k0 + c];
            Bs[r][c] = B[(size_t)(k0 + r) * Ndim + col0 + c];
        }
        __syncthreads();
#pragma unroll 8
        for (int kk = 0; kk < 32; ++kk) {
            float bv = Bs[kk][tx];
#pragma unroll
            for (int i = 0; i < 4; ++i) acc[i] += As[ty + 8 * i][kk] * bv;
        }
        __syncthreads();
    }
#pragma unroll
    for (int i = 0; i < 4; ++i)
        C[(size_t)(row0 + ty + 8 * i) * Ndim + col0 + tx] = acc[i];
}

extern "C" void kernel_launch(void* const* d_in, const int* in_sizes, int n_in,
                              void* d_out, int out_size, void* d_ws, size_t ws_size,
                              hipStream_t stream) {
    const float* x = (const float*)d_in[0];
    const float* y = (const float*)d_in[1];
    float* out = (float*)d_out;

    const size_t elemsA = (size_t)Mdim * Kdim;
    const size_t elemsB = (size_t)Ndim * Kdim;
    const size_t need   = (elemsA + elemsB) * sizeof(unsigned short);  // 64 MiB

    if (ws_size >= need) {
        unsigned short* Abf = (unsigned short*)d_ws;
        unsigned short* Btb = Abf + elemsA;

        conv_a<<<(unsigned)(elemsA / 4 / 256), 256, 0, stream>>>(x, Abf);
        conv_bt<<<dim3(Ndim / 64, Kdim / 64), 256, 0, stream>>>(y, Btb);
        gemm_bt<<<dim3(Ndim / 128, Mdim / 128), 256, 0, stream>>>(Abf, Btb, out);
    } else {
        gemm_f32_naive<<<dim3(Ndim / 32, Mdim / 32), 256, 0, stream>>>(x, y, out);
    }
}

// Round 2
// 153.628 us; speedup vs baseline: 1.4591x; 1.4591x over previous
//
#include <hip/hip_runtime.h>
#include <stdint.h>

#define Mdim 4096
#define Kdim 4096
#define Ndim 4096

typedef __attribute__((ext_vector_type(8))) short bf16x8;   // 8 bf16 (MFMA A/B frag)
typedef __attribute__((ext_vector_type(4))) float f32x4;    // MFMA C/D frag

// f32 -> bf16 round-to-nearest-even
static __device__ __forceinline__ unsigned short f2bf_rne(float f) {
    union { float f; unsigned u; } v; v.f = f;
    unsigned u = v.u;
    u += 0x7FFFu + ((u >> 16) & 1u);
    return (unsigned short)(u >> 16);
}

// async global->LDS, 16B/lane; LDS dest = wave-uniform base + lane*16 (linear).
static __device__ __forceinline__ void gload_lds16(const unsigned short* g, unsigned short* l) {
    __builtin_amdgcn_global_load_lds(
        (const __attribute__((address_space(1))) unsigned int*)g,
        (__attribute__((address_space(3))) unsigned int*)l,
        16, 0, 0);
}

// fenced barrier: raw s_barrier (no vmcnt drain) + compiler memory fences so
// LDS/global ops cannot be moved across it by the scheduler.
#define BAR()  do { asm volatile("" ::: "memory"); __builtin_amdgcn_s_barrier(); asm volatile("" ::: "memory"); } while (0)
#define LGK0() asm volatile("s_waitcnt lgkmcnt(0)" ::: "memory")
#define VMC(N) asm volatile("s_waitcnt vmcnt(" #N ")" ::: "memory")

// ---------------------------------------------------------------------------
// Conversion kernels: f32 -> bf16 (A linear, B transposed so GEMM sees B^T)
// ---------------------------------------------------------------------------
__global__ void conv_a(const float* __restrict__ a, unsigned short* __restrict__ out) {
    size_t idx = (size_t)blockIdx.x * blockDim.x + threadIdx.x;
    float4 v = ((const float4*)a)[idx];
    ushort4 o;
    o.x = f2bf_rne(v.x); o.y = f2bf_rne(v.y); o.z = f2bf_rne(v.z); o.w = f2bf_rne(v.w);
    ((ushort4*)out)[idx] = o;
}

__global__ void conv_bt(const float* __restrict__ b, unsigned short* __restrict__ bt) {
    __shared__ float tile[64][65];
    const int tn = blockIdx.x, tk = blockIdx.y;
    for (int i = threadIdx.x; i < 64 * 64; i += 256) {
        int r = i >> 6, c = i & 63;
        tile[r][c] = b[(size_t)(tk * 64 + r) * Ndim + tn * 64 + c];
    }
    __syncthreads();
    for (int i = threadIdx.x; i < 64 * 64; i += 256) {
        int n = i >> 6, k = i & 63;
        bt[(size_t)(tn * 64 + n) * Kdim + tk * 64 + k] = f2bf_rne(tile[k][n]);
    }
}

// ---------------------------------------------------------------------------
// 256x256 8-phase bf16 GEMM (C = A * B, B given as B^T).
// 512 threads = 8 waves (2M x 4N); per-wave 128x64 output = acc[8][4].
// BK=64; K-tile t -> LDS buf[t&1]. Each buf: A 2 halves (mh) + B 2 halves (nh),
// each half 128 packed rows x 64 k (16 KiB). Total LDS 128 KiB.
// A half mh holds logical rows {wm*128 + mh*64 + 0..63}; packed p = wm*64 + (r&63).
// B half nh holds logical rows {wn*64 + nh*32 + 0..31}; packed p = wn*32 + (r&31).
// Swizzle (T2): logical chunk q of packed row p lives at LDS chunk q^(p&7)
// (16B chunks). global_load_lds writes LDS linearly -> pre-swizzle the SOURCE.
// Schedule per iteration (2 K-tiles t,t+1), ds-read regions:
//   ph1: A-mh0 + B-nh0   ph2: B-nh1   ph3: A-mh1   ph4: none   (same for ph5-8)
// Stage order: ph1 AY(t+1), ph2 AX(t+2), ph3 BX(t+2), ph4 BY(t+2),
//              ph5 AY(t+2), ph6 AX(t+3), ph7 BX(t+3), ph8 BY(t+3).
// Each stage lands one phase after that region's last read. vmcnt(6) at ph4/ph8
// retires exactly one full K-tile, keeping 3 half-tiles (6 loads) in flight.
// ---------------------------------------------------------------------------
__global__ __launch_bounds__(512, 2) void gemm8p(const unsigned short* __restrict__ A,
                                                 const unsigned short* __restrict__ Bt,
                                                 float* __restrict__ C) {
    __shared__ unsigned short lds[8 * 8192];  // [buf][A0,A1,B0,B1][128*64] = 128 KiB

    const int tid  = threadIdx.x;
    const int lane = tid & 63;
    const int w    = tid >> 6;   // wave 0..7
    const int wm   = w >> 2;     // 0..1
    const int wn   = w & 3;      // 0..3

    // bijective XCD swizzle (gridDim.x = 256, 256 % 8 == 0)
    const int nchunk = gridDim.x >> 3;
    const int orig   = blockIdx.x;
    const int swz    = (orig & 7) * nchunk + (orig >> 3);
    const int bm     = swz >> 4;
    const int bn     = swz & 15;

    // ---- staging geometry: per wave, one half-tile = 2 loads (j=0,1) of 1 KiB ----
    const int pr0 = w * 8 + (lane >> 3);             // packed row for j=0
    const int c0  = ((lane & 7) ^ (pr0 & 7)) * 8;    // pre-swizzled k-chunk (elems)
    const int pr1 = 64 + pr0;                        // j=1 (pr1&7 == pr0&7)
    const int rA0 = ((pr0 >> 6) << 7) | (pr0 & 63);  // logical A row (h=0)
    const int rA1 = ((pr1 >> 6) << 7) | (pr1 & 63);
    const int rB0 = ((pr0 >> 5) << 6) | (pr0 & 31);  // logical B^T row (h=0)
    const int rB1 = ((pr1 >> 5) << 6) | (pr1 & 31);

    const unsigned short* gA0 = A  + ((size_t)(bm * 256 + rA0) << 12) + c0;
    const unsigned short* gA1 = A  + ((size_t)(bm * 256 + rA1) << 12) + c0;
    const unsigned short* gB0 = Bt + ((size_t)(bn * 256 + rB0) << 12) + c0;
    const unsigned short* gB1 = Bt + ((size_t)(bn * 256 + rB1) << 12) + c0;

    unsigned short* ldsw = lds + w * 512;  // wave's j=0 slot within a half region

#define STAGE_A(BUF, H, T) do {                                                           \
        gload_lds16(gA0 + (H) * (64 * 4096) + (T) * 64, ldsw + ((BUF) * 4 + (H)) * 8192); \
        gload_lds16(gA1 + (H) * (64 * 4096) + (T) * 64,                                   \
                    ldsw + ((BUF) * 4 + (H)) * 8192 + 4096);                              \
    } while (0)
#define STAGE_B(BUF, H, T) do {                                                               \
        gload_lds16(gB0 + (H) * (32 * 4096) + (T) * 64, ldsw + ((BUF) * 4 + 2 + (H)) * 8192); \
        gload_lds16(gB1 + (H) * (32 * 4096) + (T) * 64,                                       \
                    ldsw + ((BUF) * 4 + 2 + (H)) * 8192 + 4096);                              \
    } while (0)

    // ---- fragment reads (swizzled) ----
    const int fr = lane & 15;
    const int hi = lane >> 4;
    const int sx = fr & 7;

#define LDA_FRAG(BUF, MH, M, KK)                                                  \
    (*(const bf16x8*)((const char*)lds + ((BUF) * 4 + (MH)) * 16384 +             \
                      (wm * 64 + (M) * 16 + fr) * 128 +                           \
                      (((((KK) << 2) | hi) ^ sx) << 4)))
#define LDB_FRAG(BUF, NH, N, KK)                                                  \
    (*(const bf16x8*)((const char*)lds + ((BUF) * 4 + 2 + (NH)) * 16384 +         \
                      (wn * 32 + (N) * 16 + fr) * 128 +                           \
                      (((((KK) << 2) | hi) ^ sx) << 4)))
#define LDA_ALL(BUF, MH) do { _Pragma("unroll")                                   \
        for (int m = 0; m < 4; ++m) {                                             \
            a[m][0] = LDA_FRAG(BUF, MH, m, 0);                                    \
            a[m][1] = LDA_FRAG(BUF, MH, m, 1); } } while (0)
#define LDB_ALL(DST, BUF, NH) do { _Pragma("unroll")                              \
        for (int n = 0; n < 2; ++n) {                                             \
            DST[n][0] = LDB_FRAG(BUF, NH, n, 0);                                  \
            DST[n][1] = LDB_FRAG(BUF, NH, n, 1); } } while (0)

#define MMA_QUAD(MH, NH, BF) do {                                                 \
        __builtin_amdgcn_s_setprio(1);                                            \
        _Pragma("unroll")                                                         \
        for (int m = 0; m < 4; ++m)                                               \
            _Pragma("unroll")                                                     \
            for (int n = 0; n < 2; ++n) {                                         \
                acc[(MH)*4 + m][(NH)*2 + n] = __builtin_amdgcn_mfma_f32_16x16x32_bf16( \
                    a[m][0], BF[n][0], acc[(MH)*4 + m][(NH)*2 + n], 0, 0, 0);     \
                acc[(MH)*4 + m][(NH)*2 + n] = __builtin_amdgcn_mfma_f32_16x16x32_bf16( \
                    a[m][1], BF[n][1], acc[(MH)*4 + m][(NH)*2 + n], 0, 0, 0);     \
            }                                                                     \
        __builtin_amdgcn_s_setprio(0);                                            \
    } while (0)

    f32x4 acc[8][4] = {};
    bf16x8 a[4][2], b0[2][2], b1[2][2];

    // ---- prologue: t0 full (8 loads) + t1 AX,BX,BY (6 loads); retire t0 ----
    STAGE_A(0, 0, 0); STAGE_B(0, 0, 0); STAGE_B(0, 1, 0); STAGE_A(0, 1, 0);
    STAGE_A(1, 0, 1); STAGE_B(1, 0, 1); STAGE_B(1, 1, 1);
    VMC(6);
    BAR();

    // ---- main loop: iterations compute (t, t+1), t = 0,2,...,60 ----
    for (int i = 0; i < 31; ++i) {
        const int t = 2 * i;
        // ph1: quad(mh0,nh0) of t
        LDA_ALL(0, 0); LDB_ALL(b0, 0, 0);
        STAGE_A(1, 1, t + 1);
        BAR(); LGK0();
        MMA_QUAD(0, 0, b0);
        BAR();
        // ph2: quad(mh0,nh1)
        LDB_ALL(b1, 0, 1);
        STAGE_A(0, 0, t + 2);
        BAR(); LGK0();
        MMA_QUAD(0, 1, b1);
        BAR();
        // ph3: quad(mh1,nh1)
        LDA_ALL(0, 1);
        STAGE_B(0, 0, t + 2);
        BAR(); LGK0();
        MMA_QUAD(1, 1, b1);
        BAR();
        // ph4: quad(mh1,nh0); retire K-tile t+1
        STAGE_B(0, 1, t + 2);
        BAR();
        MMA_QUAD(1, 0, b0);
        VMC(6);
        BAR();
        // ph5: quad(mh0,nh0) of t+1
        LDA_ALL(1, 0); LDB_ALL(b0, 1, 0);
        STAGE_A(0, 1, t + 2);
        BAR(); LGK0();
        MMA_QUAD(0, 0, b0);
        BAR();
        // ph6
        LDB_ALL(b1, 1, 1);
        STAGE_A(1, 0, t + 3);
        BAR(); LGK0();
        MMA_QUAD(0, 1, b1);
        BAR();
        // ph7
        LDA_ALL(1, 1);
        STAGE_B(1, 0, t + 3);
        BAR(); LGK0();
        MMA_QUAD(1, 1, b1);
        BAR();
        // ph8: retire K-tile t+2
        STAGE_B(1, 1, t + 3);
        BAR();
        MMA_QUAD(1, 0, b0);
        VMC(6);
        BAR();
    }

    // ---- epilogue iteration: t = 62, 63 (only AY(63) left to stage) ----
    LDA_ALL(0, 0); LDB_ALL(b0, 0, 0);
    STAGE_A(1, 1, 63);
    BAR(); LGK0();
    MMA_QUAD(0, 0, b0);
    BAR();
    LDB_ALL(b1, 0, 1);
    BAR(); LGK0();
    MMA_QUAD(0, 1, b1);
    BAR();
    LDA_ALL(0, 1);
    BAR(); LGK0();
    MMA_QUAD(1, 1, b1);
    BAR();
    MMA_QUAD(1, 0, b0);
    VMC(0);
    BAR();
    LDA_ALL(1, 0); LDB_ALL(b0, 1, 0);
    BAR(); LGK0();
    MMA_QUAD(0, 0, b0);
    BAR();
    LDB_ALL(b1, 1, 1);
    BAR(); LGK0();
    MMA_QUAD(0, 1, b1);
    BAR();
    LDA_ALL(1, 1);
    BAR(); LGK0();
    MMA_QUAD(1, 1, b1);
    BAR();
    MMA_QUAD(1, 0, b0);

    // ---- C write: row = (lane>>4)*4 + reg, col = lane&15 per 16x16 frag ----
    const size_t crow = (size_t)(bm * 256 + wm * 128 + hi * 4);
    const int    ccol = bn * 256 + wn * 64 + fr;
#pragma unroll
    for (int mi = 0; mi < 8; ++mi)
#pragma unroll
        for (int ni = 0; ni < 4; ++ni) {
            const size_t row = crow + mi * 16;
            const int    col = ccol + ni * 16;
#pragma unroll
            for (int r = 0; r < 4; ++r)
                C[(row + r) * Ndim + col] = acc[mi][ni][r];
        }

#undef STAGE_A
#undef STAGE_B
#undef LDA_FRAG
#undef LDB_FRAG
#undef LDA_ALL
#undef LDB_ALL
#undef MMA_QUAD
}

// ---------------------------------------------------------------------------
// Fallback if workspace too small: plain f32 tiles
// ---------------------------------------------------------------------------
__global__ void gemm_f32_naive(const float* __restrict__ A, const float* __restrict__ B,
                               float* __restrict__ C) {
    __shared__ float As[32][33], Bs[32][33];
    const int tx = threadIdx.x & 31, ty = threadIdx.x >> 5;
    const int row0 = blockIdx.y * 32, col0 = blockIdx.x * 32;
    float acc[4] = {0.f, 0.f, 0.f, 0.f};
    for (int k0 = 0; k0 < Kdim; k0 += 32) {
        for (int i = threadIdx.x; i < 32 * 32; i += 256) {
            int r = i >> 5, c = i & 31;
            As[r][c] = A[(size_t)(row0 + r) * Kdim + k0 + c];
            Bs[r][c] = B[(size_t)(k0 + r) * Ndim + col0 + c];
        }
        __syncthreads();
#pragma unroll 8
        for (int kk = 0; kk < 32; ++kk) {
            float bv = Bs[kk][tx];
#pragma unroll
            for (int i = 0; i < 4; ++i) acc[i] += As[ty + 8 * i][kk] * bv;
        }
        __syncthreads();
    }
#pragma unroll
    for (int i = 0; i < 4; ++i)
        C[(size_t)(row0 + ty + 8 * i) * Ndim + col0 + tx] = acc[i];
}

extern "C" void kernel_launch(void* const* d_in, const int* in_sizes, int n_in,
                              void* d_out, int out_size, void* d_ws, size_t ws_size,
                              hipStream_t stream) {
    const float* x = (const float*)d_in[0];
    const float* y = (const float*)d_in[1];
    float* out = (float*)d_out;

    const size_t elemsA = (size_t)Mdim * Kdim;
    const size_t elemsB = (size_t)Ndim * Kdim;
    const size_t need   = (elemsA + elemsB) * sizeof(unsigned short);  // 64 MiB

    if (ws_size >= need) {
        unsigned short* Abf = (unsigned short*)d_ws;
        unsigned short* Btb = Abf + elemsA;

        conv_a<<<(unsigned)(elemsA / 4 / 256), 256, 0, stream>>>(x, Abf);
        conv_bt<<<dim3(Ndim / 64, Kdim / 64), 256, 0, stream>>>(y, Btb);
        gemm8p<<<dim3((Mdim / 256) * (Ndim / 256)), 512, 0, stream>>>(Abf, Btb, out);
    } else {
        gemm_f32_naive<<<dim3(Ndim / 32, Mdim / 32), 256, 0, stream>>>(x, y, out);
    }
}